// Round 6
// baseline (267.401 us; speedup 1.0000x reference)
//
#include <hip/hip_runtime.h>
#include <math.h>

// Problem constants (from reference)
#define N_ROWS 8192
#define B_CH   64
#define L_SEQ  256
#define D_DIM  128
#define KEEP   64
#define HID    1024
#define KTOT   8320            // 128 (q) + 64*128 (packed); log_count handled in epilogue
#define KTILES 260             // KTOT/32
#define HTILES 64              // HID/16

// bf16 staging buffer layout (elements)
#define KOFF   (N_ROWS * D_DIM)              // 1,048,576  : start of k-chains
#define ZOFF   (KOFF + B_CH * L_SEQ * D_DIM) // 3,145,728  : zero page (128 elems)
#define BUF_ELEMS (ZOFF + 128)               // 3,145,856

// prep task partition (pack FIRST: latency-bound blocks start early; out-init folded in)
#define PACK_BLOCKS 256                      // 32 rows each (+ out[n]=b2)
#define QK_BLOCKS   1537                     // ceil(393232/256)
#define W1T_BLOCKS  2080                     // 130 k64-tiles x 16 h64-tiles
#define PREP_GRID   (PACK_BLOCKS + QK_BLOCKS + W1T_BLOCKS)

typedef unsigned short ushort_t;
typedef __attribute__((ext_vector_type(8))) short  short8;   // 8 bf16 = 4 VGPRs (MFMA A/B frag)
typedef __attribute__((ext_vector_type(4))) float  float4v;  // MFMA C/D frag

// fp32 -> bf16 round-to-nearest-even (inputs finite; no NaN handling needed)
__device__ __forceinline__ ushort_t f2bf(float f) {
    union { float f; unsigned int u; } v; v.f = f;
    unsigned int u = v.u;
    unsigned int r = u + 0x7fffu + ((u >> 16) & 1u);
    return (ushort_t)(r >> 16);
}

// async global->LDS, 16B per lane; LDS dest = wave-uniform base + lane*16.
// Compiler-visible VMEM (tracked by the waitcnt pass).
__device__ __forceinline__ void glds16(const void* g, void* l) {
    __builtin_amdgcn_global_load_lds(
        (const __attribute__((address_space(1))) unsigned int*)g,
        (__attribute__((address_space(3))) unsigned int*)l,
        16, 0, 0);
}

#define SCHED0() __builtin_amdgcn_sched_barrier(0)
// Manual counted wait (cross-wave LDS-staging guarantee the compiler can't
// derive).  rule #18: sched_barrier(0) right after.
#define WAITVM(n) do { asm volatile("s_waitcnt vmcnt(" #n ")" ::: "memory"); SCHED0(); } while (0)

// ---- fused prep: pack(+out) | conv_qk | conv_w1frag in ONE dispatch ------
// (R4-verified form; R5's cross-iteration output caching is INVALID: the
// harness re-poisons d_ws between iterations, so cached srcLUT became
// garbage gather offsets -> aperture fault.)
// w1frag layout: for (h,k): hT=h>>4, ln=h&15, kT=k>>5, quad=(k>>3)&3, j=k&7
//   elem addr = ((hT*KTILES + kT)*64 + (quad*16+ln))*8 + j
__global__ void prep(const float* __restrict__ q, const float* __restrict__ k,
                     const float* __restrict__ W1, const int* __restrict__ mask,
                     const int* __restrict__ batch_idx, const int* __restrict__ count,
                     const float* __restrict__ b2,
                     ushort_t* __restrict__ buf, ushort_t* __restrict__ w1f,
                     int* __restrict__ srcLUT, float* __restrict__ logc,
                     float* __restrict__ out) {
    __shared__ __align__(16) char smem[16640];   // max(w1t tile 16640, pack 8448)
    const int blk = blockIdx.x;
    const int t = threadIdx.x;

    if (blk < PACK_BLOCKS) {
        // ---- pack: 32 rows/block; ballot-rank; coalesced LUT writes; out init ----
        const int n0 = blk * 32;
        int* sidx = (int*)smem;                    // [32][65] (pad 65 -> conflict-free)
        int* bidx_l = (int*)(smem + 32 * 65 * 4);  // [32]
        for (int i = t; i < 32 * 65; i += 256) sidx[i] = -1;
        if (t < 32) {
            int n = n0 + t;
            bidx_l[t] = batch_idx[n];
            logc[n] = log1pf((float)count[n]);
            srcLUT[n] = n * D_DIM;                 // bi=0: q row offset
            out[n] = b2[0];                        // atomic accumulation base
        }
        __syncthreads();
        const int w = t >> 6, l = t & 63;
        const unsigned long long ltm = (1ull << l) - 1ull;
        for (int r = 0; r < 8; ++r) {              // wave w: rows w*8 .. w*8+7
            const int lr = w * 8 + r;
            const int* mrow = mask + (size_t)(n0 + lr) * L_SEQ;
            int m0 = mrow[l] != 0;
            int m1 = mrow[64 + l] != 0;
            int m2 = mrow[128 + l] != 0;
            int m3 = mrow[192 + l] != 0;
            unsigned long long b0 = __ballot(m0), b1 = __ballot(m1);
            unsigned long long b2v = __ballot(m2), b3 = __ballot(m3);
            int p1 = (int)__popcll(b0);
            int p2 = p1 + (int)__popcll(b1);
            int p3 = p2 + (int)__popcll(b2v);
            int* row = sidx + lr * 65;
            if (m0) { int rk = (int)__popcll(b0 & ltm);       if (rk < KEEP) row[rk] = l; }
            if (m1) { int rk = p1 + (int)__popcll(b1 & ltm);  if (rk < KEEP) row[rk] = 64 + l; }
            if (m2) { int rk = p2 + (int)__popcll(b2v & ltm); if (rk < KEEP) row[rk] = 128 + l; }
            if (m3) { int rk = p3 + (int)__popcll(b3 & ltm);  if (rk < KEEP) row[rk] = 192 + l; }
        }
        __syncthreads();
        // write phase: per j, 32 consecutive n -> 128-B coalesced segments
        for (int e = t; e < KEEP * 32; e += 256) {
            int j = e >> 5, nl = e & 31;
            int s = sidx[nl * 65 + j];
            srcLUT[(size_t)(j + 1) * N_ROWS + n0 + nl] =
                (s >= 0) ? (KOFF + (bidx_l[nl] * L_SEQ + s) * D_DIM) : ZOFF;
        }

    } else if (blk < PACK_BLOCKS + QK_BLOCKS) {
        // ---- q,k -> bf16 buf + zero page ----
        int c = (blk - PACK_BLOCKS) * 256 + t;
        if (c >= BUF_ELEMS / 8) return;
        int e = c * 8;
        float4 x0, x1;
        if (e < KOFF) {
            const float4* s = (const float4*)(q + e);
            x0 = s[0]; x1 = s[1];
        } else if (e < ZOFF) {
            const float4* s = (const float4*)(k + (e - KOFF));
            x0 = s[0]; x1 = s[1];
        } else {
            x0 = make_float4(0.f, 0.f, 0.f, 0.f);
            x1 = x0;
        }
        union { ushort_t s[8]; uint4 v; } o;
        o.s[0] = f2bf(x0.x); o.s[1] = f2bf(x0.y); o.s[2] = f2bf(x0.z); o.s[3] = f2bf(x0.w);
        o.s[4] = f2bf(x1.x); o.s[5] = f2bf(x1.y); o.s[6] = f2bf(x1.z); o.s[7] = f2bf(x1.w);
        *(uint4*)(buf + e) = o.v;

    } else {
        // ---- W1 -> bf16 in MFMA-fragment order (LDS-transposed 64x64 tile) ----
        const int idx = blk - (PACK_BLOCKS + QK_BLOCKS);
        const int k0 = (idx % 130) * 64, h0 = (idx / 130) * 64;
        float (*tile)[65] = (float(*)[65])smem;   // +1 pad
        const int r0 = t >> 4, c4 = (t & 15) * 4;
#pragma unroll
        for (int i = 0; i < 4; ++i) {
            const int r = r0 + i * 16;
            const float4 v = *(const float4*)(W1 + (size_t)(k0 + r) * HID + h0 + c4);
            tile[r][c4 + 0] = v.x; tile[r][c4 + 1] = v.y;
            tile[r][c4 + 2] = v.z; tile[r][c4 + 3] = v.w;
        }
        __syncthreads();
        // 8 chunks of 1KB: chunk c = qt*4 + ht; slot s = i*256 + t
#pragma unroll
        for (int i = 0; i < 2; ++i) {
            int s = i * 256 + t;
            int c = s >> 6, l = s & 63;
            int qt = c >> 2, ht = c & 3;
            int ln = l & 15, quad = l >> 4;
            union { ushort_t sv[8]; uint4 v; } o;
#pragma unroll
            for (int j = 0; j < 8; ++j)
                o.sv[j] = f2bf(tile[qt * 32 + quad * 8 + j][ht * 16 + ln]);
            size_t dst = (((size_t)(h0 / 16 + ht) * KTILES + (k0 / 32 + qt)) * 64 + l) * 8;
            *(uint4*)(w1f + dst) = o.v;
        }
    }
}

// ---- gemm: gather-GEMM + gelu + @W2 --------------------------------------
// R0 iteration shape preserved (BK=128, 64 MFMA per barrier-pair, B loaded
// in-iteration) -- the ONLY change vs R0: the gather glds is issued ONE
// iteration ahead into a double-buffered As (64 KB LDS, still 2 blocks/CU),
// drained by a counted WAITVM(32) instead of __syncthreads' vmcnt(0).
// Ledger per half t (issue order): B(t)x16 | LUT(t+2)x8 | glds(t+1)x8 |
// WAITVM(32) -> ops newer than glds(t) = 16+8+8 = 32 exactly, so glds(t)
// (issued LAST half, a full MFMA phase ago) is drained with full latency
// cover.  Compiler auto-waits for B/LUT values compute to vmcnt(>=24) by
// position arithmetic -> they never force-drain the in-flight glds.
// Spill insertions only deepen glds' position -> WAITVM(32) stays safe.
// Raw s_barrier (not __syncthreads) keeps prefetches alive across barriers.
// R3's failure mode (halved MFMA/barrier + doubled barriers) is avoided.
__global__ __launch_bounds__(256, 2)
void gemm_mlp(const ushort_t* __restrict__ buf, const ushort_t* __restrict__ w1f,
              const int* __restrict__ srcLUT, const float* __restrict__ logc,
              const float* __restrict__ W1, const float* __restrict__ b1,
              const float* __restrict__ W2, float* __restrict__ out) {
    __shared__ __align__(16) ushort_t As0[128 * 128];   // 32 KB, even tiles
    __shared__ __align__(16) ushort_t As1[128 * 128];   // 32 KB, odd tiles

    const int t = threadIdx.x;
    const int blkH = blockIdx.x, blkM = blockIdx.y;   // x=8 -> XCD-pinned B slice
    const int wave = t >> 6, lane = t & 63;
    const int wm = wave >> 1, wh = wave & 1;
    const int ln = lane & 15, quad = lane >> 4;

    float4v acc[4][4];
#pragma unroll
    for (int i = 0; i < 4; ++i)
#pragma unroll
        for (int j = 0; j < 4; ++j)
#pragma unroll
            for (int r = 0; r < 4; ++r) acc[i][j][r] = 0.0f;

    // A staging: pass i (0..7), chunk c=i*256+t; row=i*16+(t>>4); LDS slot=t&15;
    // global piece pg = slot ^ (row&15) = (t&15)^(t>>4)  (pass-invariant).
    const int tr = t >> 4;
    const int pg = (t & 15) ^ tr;
    ushort_t* lA0 = As0 + t * 8;
    ushort_t* lA1 = As1 + t * 8;
    const int* lutBase = srcLUT + blkM * 128 + tr;

    // B fragment pointers: per ni, chunk base for (hT = blkH*8 + wh*4 + ni),
    // lane-contiguous: + lane*8 elems; per (tile,kk): + (tile*4+kk)*512 elems.
    const ushort_t* bp[4];
#pragma unroll
    for (int ni = 0; ni < 4; ++ni)
        bp[ni] = w1f + ((size_t)(blkH * 8 + wh * 4 + ni) * KTILES * 64 + lane) * 8;

    int offE[8], offO[8];   // gather offsets for the next even / odd tile

    // ---- prologue: LUT(0) -> glds(0)->As0 ; LUT(1)->offO ----
    {
        int offP[8];
#pragma unroll
        for (int i = 0; i < 8; ++i) offP[i] = lutBase[i * 16];               // LUT(0)
#pragma unroll
        for (int i = 0; i < 8; ++i) glds16(buf + offP[i] + pg * 8, lA0 + i * 2048);
#pragma unroll
        for (int i = 0; i < 8; ++i) offO[i] = lutBase[(size_t)N_ROWS + i * 16]; // LUT(1)
        SCHED0();
    }

#pragma unroll 1
    for (int m = 0; m < 32; ++m) {
        // ======== even half: compute tile 2m (As0) ========
        {
            short8 bq[4][4];
#pragma unroll
            for (int kk = 0; kk < 4; ++kk)
#pragma unroll
                for (int ni = 0; ni < 4; ++ni)
                    bq[kk][ni] = *(const short8*)(bp[ni] + (size_t)(2 * m * 4 + kk) * 512);
            SCHED0();
#pragma unroll
            for (int i = 0; i < 8; ++i)                                       // LUT(2m+2)
                offE[i] = lutBase[(size_t)(2 * m + 2) * N_ROWS + i * 16];
            SCHED0();
#pragma unroll
            for (int i = 0; i < 8; ++i)                                       // glds(2m+1)->As1
                glds16(buf + offO[i] + pg * 8, lA1 + i * 2048);
            SCHED0();
            WAITVM(32);                      // drains glds(2m) (issued last half)
            __builtin_amdgcn_s_barrier();
            SCHED0();
            __builtin_amdgcn_s_setprio(1);
#pragma unroll
            for (int kk = 0; kk < 4; ++kk) {
                short8 af[4];
#pragma unroll
                for (int mi = 0; mi < 4; ++mi) {
                    const int row = wm * 64 + mi * 16 + ln;
                    const int sl = (kk * 4 + quad) ^ ln;
                    af[mi] = *(const short8*)(As0 + row * 128 + sl * 8);
                }
#pragma unroll
                for (int mi = 0; mi < 4; ++mi)
#pragma unroll
                    for (int ni = 0; ni < 4; ++ni)
                        acc[mi][ni] = __builtin_amdgcn_mfma_f32_16x16x32_bf16(
                            af[mi], bq[kk][ni], acc[mi][ni], 0, 0, 0);
            }
            __builtin_amdgcn_s_setprio(0);
            SCHED0();
            __builtin_amdgcn_s_barrier();    // all waves done reading As0
            SCHED0();
        }

        // ======== odd half: compute tile 2m+1 (As1) ========
        {
            short8 bq[4][4];
#pragma unroll
            for (int kk = 0; kk < 4; ++kk)
#pragma unroll
                for (int ni = 0; ni < 4; ++ni)
                    bq[kk][ni] = *(const short8*)(bp[ni] + (size_t)((2 * m + 1) * 4 + kk) * 512);
            SCHED0();
            const int tl = (2 * m + 3 > 64) ? 64 : (2 * m + 3);               // LUT(2m+3) clamped
#pragma unroll
            for (int i = 0; i < 8; ++i)
                offO[i] = lutBase[(size_t)tl * N_ROWS + i * 16];
            SCHED0();
#pragma unroll
            for (int i = 0; i < 8; ++i)                                       // glds(2m+2)->As0
                glds16(buf + offE[i] + pg * 8, lA0 + i * 2048);
            SCHED0();
            WAITVM(32);                      // drains glds(2m+1)
            __builtin_amdgcn_s_barrier();
            SCHED0();
            __builtin_amdgcn_s_setprio(1);
#pragma unroll
            for (int kk = 0; kk < 4; ++kk) {
                short8 af[4];
#pragma unroll
                for (int mi = 0; mi < 4; ++mi) {
                    const int row = wm * 64 + mi * 16 + ln;
                    const int sl = (kk * 4 + quad) ^ ln;
                    af[mi] = *(const short8*)(As1 + row * 128 + sl * 8);
                }
#pragma unroll
                for (int mi = 0; mi < 4; ++mi)
#pragma unroll
                    for (int ni = 0; ni < 4; ++ni)
                        acc[mi][ni] = __builtin_amdgcn_mfma_f32_16x16x32_bf16(
                            af[mi], bq[kk][ni], acc[mi][ni], 0, 0, 0);
            }
            __builtin_amdgcn_s_setprio(0);
            SCHED0();
            __builtin_amdgcn_s_barrier();    // all waves done reading As1
            SCHED0();
        }
    }
    // keep-alive: last iteration's offO loads must stay in the binary so the
    // WAITVM(32) ledger keeps its 32-newer guarantee (rule #17).
#pragma unroll
    for (int i = 0; i < 8; ++i) asm volatile("" :: "v"(offO[i]));

    // ---- peeled tile 64 (staged into As0 by the m=31 odd half) ----
    {
        short8 bq[4][4];
#pragma unroll
        for (int kk = 0; kk < 4; ++kk)
#pragma unroll
            for (int ni = 0; ni < 4; ++ni)
                bq[kk][ni] = *(const short8*)(bp[ni] + (size_t)(64 * 4 + kk) * 512);
        SCHED0();
        WAITVM(0);                           // full drain (one-time tail stall)
        __builtin_amdgcn_s_barrier();
        SCHED0();
#pragma unroll
        for (int kk = 0; kk < 4; ++kk) {
            short8 af[4];
#pragma unroll
            for (int mi = 0; mi < 4; ++mi) {
                const int row = wm * 64 + mi * 16 + ln;
                const int sl = (kk * 4 + quad) ^ ln;
                af[mi] = *(const short8*)(As0 + row * 128 + sl * 8);
            }
#pragma unroll
            for (int mi = 0; mi < 4; ++mi)
#pragma unroll
                for (int ni = 0; ni < 4; ++ni)
                    acc[mi][ni] = __builtin_amdgcn_mfma_f32_16x16x32_bf16(
                        af[mi], bq[kk][ni], acc[mi][ni], 0, 0, 0);
        }
    }

    // Epilogue: pre = acc + logc[n]*W1[last,h] + b1[h]; gelu(exact); dot W2; atomic out.
    // C/D layout (verified m89/m91): col = lane&15 (h), row = quad*4 + reg (n).
    const float* w1last = W1 + (size_t)KTOT * HID;
    float w1l[4], b1v[4], w2v[4];
#pragma unroll
    for (int ni = 0; ni < 4; ++ni) {
        int h = blkH * 128 + wh * 64 + ni * 16 + ln;
        w1l[ni] = w1last[h];
        b1v[ni] = b1[h];
        w2v[ni] = W2[h];
    }
    const int nbase = blkM * 128 + wm * 64 + quad * 4;
#pragma unroll
    for (int mi = 0; mi < 4; ++mi) {
#pragma unroll
        for (int rg = 0; rg < 4; ++rg) {
            const int n = nbase + mi * 16 + rg;
            const float lc = logc[n];
            float s = 0.0f;
#pragma unroll
            for (int ni = 0; ni < 4; ++ni) {
                float pre = acc[mi][ni][rg] + lc * w1l[ni] + b1v[ni];
                float hv = 0.5f * pre * (1.0f + erff(pre * 0.70710678118654752f));
                s += hv * w2v[ni];
            }
            s += __shfl_xor(s, 1);
            s += __shfl_xor(s, 2);
            s += __shfl_xor(s, 4);
            s += __shfl_xor(s, 8);
            if (ln == 0) atomicAdd(out + n, s);
        }
    }
}

// ---- launch --------------------------------------------------------------
extern "C" void kernel_launch(void* const* d_in, const int* in_sizes, int n_in,
                              void* d_out, int out_size, void* d_ws, size_t ws_size,
                              hipStream_t stream) {
    const float* q     = (const float*)d_in[0];
    const float* k     = (const float*)d_in[1];
    const int*   bidx  = (const int*)d_in[2];
    const int*   mask  = (const int*)d_in[3];
    const int*   count = (const int*)d_in[4];
    const float* W1    = (const float*)d_in[5];
    const float* b1    = (const float*)d_in[6];
    const float* W2    = (const float*)d_in[7];
    const float* b2    = (const float*)d_in[8];
    float* out = (float*)d_out;

    // workspace layout (bytes): buf 6,291,712 | w1f 17,039,360 | srcLUT 2,129,920 | logc 32,768
    char* ws = (char*)d_ws;
    ushort_t* buf    = (ushort_t*)(ws);
    ushort_t* w1f    = (ushort_t*)(ws + 6291712);
    int*      srcLUT = (int*)(ws + 6291712 + 17039360);
    float*    logc   = (float*)(ws + 6291712 + 17039360 + 2129920);

    prep<<<PREP_GRID, 256, 0, stream>>>(q, k, W1, mask, bidx, count, b2,
                                        buf, w1f, srcLUT, logc, out);
    gemm_mlp<<<dim3(HID / 128, N_ROWS / 128), 256, 0, stream>>>(
        buf, w1f, srcLUT, logc, W1, b1, W2, out);
}

// Round 7
// 247.687 us; speedup vs baseline: 1.0796x; 1.0796x over previous
//
#include <hip/hip_runtime.h>
#include <math.h>

// Problem constants (from reference)
#define N_ROWS 8192
#define B_CH   64
#define L_SEQ  256
#define D_DIM  128
#define KEEP   64
#define HID    1024
#define KTOT   8320            // 128 (q) + 64*128 (packed); log_count handled in epilogue
#define KTILES 260             // KTOT/32
#define HTILES 64              // HID/16

// bf16 staging buffer layout (elements)
#define KOFF   (N_ROWS * D_DIM)              // 1,048,576  : start of k-chains
#define ZOFF   (KOFF + B_CH * L_SEQ * D_DIM) // 3,145,728  : zero page (128 elems)
#define BUF_ELEMS (ZOFF + 128)               // 3,145,856

#define PACK_BLOCKS 256                      // 32 rows each (+ out[n]=b2)
#define QK_BLOCKS   1537                     // ceil(393232/256)
#define W1T_BLOCKS  2080                     // 130 k64-tiles x 16 h64-tiles

typedef unsigned short ushort_t;
typedef __attribute__((ext_vector_type(8))) short  short8;   // 8 bf16 = 4 VGPRs (MFMA A/B frag)
typedef __attribute__((ext_vector_type(4))) float  float4v;  // MFMA C/D frag

// fp32 -> bf16 round-to-nearest-even (inputs finite; no NaN handling needed)
__device__ __forceinline__ ushort_t f2bf(float f) {
    union { float f; unsigned int u; } v; v.f = f;
    unsigned int u = v.u;
    unsigned int r = u + 0x7fffu + ((u >> 16) & 1u);
    return (ushort_t)(r >> 16);
}

// async global->LDS, 16B per lane; LDS dest = wave-uniform base + lane*16.
__device__ __forceinline__ void glds16(const void* g, void* l) {
    __builtin_amdgcn_global_load_lds(
        (const __attribute__((address_space(1))) unsigned int*)g,
        (__attribute__((address_space(3))) unsigned int*)l,
        16, 0, 0);
}

// ---- prep phase 1: pack (ballot-rank subset -> srcLUT) + logc + out init --
// (R6 post-mortem: prep carries ~70 us of non-BW overhead with no per-phase
// attribution -- rank-6, invisible in top-5.  This round splits prep 3-way,
// logic byte-identical, purely so each phase gets its own counter row.)
__global__ void prep_pack(const int* __restrict__ mask,
                          const int* __restrict__ batch_idx,
                          const int* __restrict__ count,
                          const float* __restrict__ b2,
                          int* __restrict__ srcLUT, float* __restrict__ logc,
                          float* __restrict__ out) {
    __shared__ __align__(16) char smem[8448];
    const int blk = blockIdx.x;
    const int t = threadIdx.x;

    const int n0 = blk * 32;
    int* sidx = (int*)smem;                    // [32][65] (pad 65 -> conflict-free)
    int* bidx_l = (int*)(smem + 32 * 65 * 4);  // [32]
    for (int i = t; i < 32 * 65; i += 256) sidx[i] = -1;
    if (t < 32) {
        int n = n0 + t;
        bidx_l[t] = batch_idx[n];
        logc[n] = log1pf((float)count[n]);
        srcLUT[n] = n * D_DIM;                 // bi=0: q row offset
        out[n] = b2[0];                        // atomic accumulation base
    }
    __syncthreads();
    const int w = t >> 6, l = t & 63;
    const unsigned long long ltm = (1ull << l) - 1ull;
    for (int r = 0; r < 8; ++r) {              // wave w: rows w*8 .. w*8+7
        const int lr = w * 8 + r;
        const int* mrow = mask + (size_t)(n0 + lr) * L_SEQ;
        int m0 = mrow[l] != 0;
        int m1 = mrow[64 + l] != 0;
        int m2 = mrow[128 + l] != 0;
        int m3 = mrow[192 + l] != 0;
        unsigned long long b0 = __ballot(m0), b1 = __ballot(m1);
        unsigned long long b2v = __ballot(m2), b3 = __ballot(m3);
        int p1 = (int)__popcll(b0);
        int p2 = p1 + (int)__popcll(b1);
        int p3 = p2 + (int)__popcll(b2v);
        int* row = sidx + lr * 65;
        if (m0) { int rk = (int)__popcll(b0 & ltm);       if (rk < KEEP) row[rk] = l; }
        if (m1) { int rk = p1 + (int)__popcll(b1 & ltm);  if (rk < KEEP) row[rk] = 64 + l; }
        if (m2) { int rk = p2 + (int)__popcll(b2v & ltm); if (rk < KEEP) row[rk] = 128 + l; }
        if (m3) { int rk = p3 + (int)__popcll(b3 & ltm);  if (rk < KEEP) row[rk] = 192 + l; }
    }
    __syncthreads();
    // write phase: per j, 32 consecutive n -> 128-B coalesced segments
    for (int e = t; e < KEEP * 32; e += 256) {
        int j = e >> 5, nl = e & 31;
        int s = sidx[nl * 65 + j];
        srcLUT[(size_t)(j + 1) * N_ROWS + n0 + nl] =
            (s >= 0) ? (KOFF + (bidx_l[nl] * L_SEQ + s) * D_DIM) : ZOFF;
    }
}

// ---- prep phase 2: q,k -> bf16 buf + zero page ----------------------------
__global__ void prep_qk(const float* __restrict__ q, const float* __restrict__ k,
                        ushort_t* __restrict__ buf) {
    int c = blockIdx.x * 256 + threadIdx.x;
    if (c >= BUF_ELEMS / 8) return;
    int e = c * 8;
    float4 x0, x1;
    if (e < KOFF) {
        const float4* s = (const float4*)(q + e);
        x0 = s[0]; x1 = s[1];
    } else if (e < ZOFF) {
        const float4* s = (const float4*)(k + (e - KOFF));
        x0 = s[0]; x1 = s[1];
    } else {
        x0 = make_float4(0.f, 0.f, 0.f, 0.f);
        x1 = x0;
    }
    union { ushort_t s[8]; uint4 v; } o;
    o.s[0] = f2bf(x0.x); o.s[1] = f2bf(x0.y); o.s[2] = f2bf(x0.z); o.s[3] = f2bf(x0.w);
    o.s[4] = f2bf(x1.x); o.s[5] = f2bf(x1.y); o.s[6] = f2bf(x1.z); o.s[7] = f2bf(x1.w);
    *(uint4*)(buf + e) = o.v;
}

// ---- prep phase 3: W1 -> bf16 in MFMA-fragment order ----------------------
// w1frag layout: for (h,k): hT=h>>4, ln=h&15, kT=k>>5, quad=(k>>3)&3, j=k&7
//   elem addr = ((hT*KTILES + kT)*64 + (quad*16+ln))*8 + j
// so a gemm wave's B-frag load (lane l = quad*16+ln) is base + l*16B: 1KB contiguous.
__global__ void prep_w1(const float* __restrict__ W1, ushort_t* __restrict__ w1f) {
    __shared__ __align__(16) char smem[16640];
    const int idx = blockIdx.x;
    const int t = threadIdx.x;
    const int k0 = (idx % 130) * 64, h0 = (idx / 130) * 64;
    float (*tile)[65] = (float(*)[65])smem;   // +1 pad
    const int r0 = t >> 4, c4 = (t & 15) * 4;
#pragma unroll
    for (int i = 0; i < 4; ++i) {
        const int r = r0 + i * 16;
        const float4 v = *(const float4*)(W1 + (size_t)(k0 + r) * HID + h0 + c4);
        tile[r][c4 + 0] = v.x; tile[r][c4 + 1] = v.y;
        tile[r][c4 + 2] = v.z; tile[r][c4 + 3] = v.w;
    }
    __syncthreads();
    // 8 chunks of 1KB: chunk c = qt*4 + ht; slot s = i*256 + t
#pragma unroll
    for (int i = 0; i < 2; ++i) {
        int s = i * 256 + t;
        int c = s >> 6, l = s & 63;
        int qt = c >> 2, ht = c & 3;
        int ln = l & 15, quad = l >> 4;
        union { ushort_t sv[8]; uint4 v; } o;
#pragma unroll
        for (int j = 0; j < 8; ++j)
            o.sv[j] = f2bf(tile[qt * 32 + quad * 8 + j][ht * 16 + ln]);
        size_t dst = (((size_t)(h0 / 16 + ht) * KTILES + (k0 / 32 + qt)) * 64 + l) * 8;
        *(uint4*)(w1f + dst) = o.v;
    }
}

// ---- gemm: gather-GEMM + gelu + @W2; A via LDS, B DIRECT from L2 ---------
// R0/R4-verified structure VERBATIM (147 us, MfmaUtil 42.8%, ~950 TF = this
// structure's ceiling).  Hand-scheduling grafts (R3 counted-vmcnt split, R6
// prefetch+WAITVM+SCHED0 walls) both regressed ~25% -- m141 failure mode:
// order-pinning defeats the compiler's own scheduling.  Frozen.
__global__ __launch_bounds__(256, 2)
void gemm_mlp(const ushort_t* __restrict__ buf, const ushort_t* __restrict__ w1f,
              const int* __restrict__ srcLUT, const float* __restrict__ logc,
              const float* __restrict__ W1, const float* __restrict__ b1,
              const float* __restrict__ W2, float* __restrict__ out) {
    __shared__ ushort_t As[128 * 128];   // 32 KB, [row][k] with 16B-slot XOR swizzle

    const int t = threadIdx.x;
    const int blkH = blockIdx.x, blkM = blockIdx.y;   // x=8 -> XCD-pinned B slice
    const int wave = t >> 6, lane = t & 63;
    const int wm = wave >> 1, wh = wave & 1;
    const int ln = lane & 15, quad = lane >> 4;

    float4v acc[4][4];
#pragma unroll
    for (int i = 0; i < 4; ++i)
#pragma unroll
        for (int j = 0; j < 4; ++j)
#pragma unroll
            for (int r = 0; r < 4; ++r) acc[i][j][r] = 0.0f;

    // A staging: pass i (0..7), chunk c=i*256+t; row=i*16+(t>>4); LDS slot=t&15;
    // global piece pg = slot ^ (row&15) = (t&15)^(t>>4)  (pass-invariant).
    const int tr = t >> 4;
    const int pg = (t & 15) ^ tr;
    ushort_t* lA = As + t * 8;
    const int* lutBase = srcLUT + blkM * 128 + tr;

    // B fragment pointers: per ni, chunk base for (hT = blkH*8 + wh*4 + ni),
    // lane-contiguous: + lane*8 elems; per (bi,kk): + (bi*4+kk)*512 elems.
    const ushort_t* bp[4];
#pragma unroll
    for (int ni = 0; ni < 4; ++ni)
        bp[ni] = w1f + ((size_t)(blkH * 8 + wh * 4 + ni) * KTILES * 64 + lane) * 8;

    int offA[8];
#pragma unroll
    for (int i = 0; i < 8; ++i) offA[i] = lutBase[i * 16];   // bi = 0 (q rows)

    for (int bi = 0; bi < 65; ++bi) {
        // stage A(bi) into LDS
#pragma unroll
        for (int i = 0; i < 8; ++i)
            glds16(buf + offA[i] + pg * 8, lA + i * 2048);
        // load all B(bi) fragments into registers (drained by the same barrier)
        short8 bq[4][4];
#pragma unroll
        for (int kk = 0; kk < 4; ++kk)
#pragma unroll
            for (int ni = 0; ni < 4; ++ni)
                bq[kk][ni] = *(const short8*)(bp[ni] + (size_t)(bi * 4 + kk) * 512);
        // prefetch next bi's gather offsets
        int offN[8];
        if (bi < 64) {
#pragma unroll
            for (int i = 0; i < 8; ++i) offN[i] = lutBase[(bi + 1) * N_ROWS + i * 16];
        }
        __syncthreads();                      // drains vmcnt (glds + B loads)
#pragma unroll
        for (int kk = 0; kk < 4; ++kk) {
            short8 af[4];
#pragma unroll
            for (int mi = 0; mi < 4; ++mi) {
                const int row = wm * 64 + mi * 16 + ln;          // row&15 == ln
                const int sl = (kk * 4 + quad) ^ ln;
                af[mi] = *(const short8*)(As + row * 128 + sl * 8);
            }
#pragma unroll
            for (int mi = 0; mi < 4; ++mi)
#pragma unroll
                for (int ni = 0; ni < 4; ++ni)
                    acc[mi][ni] = __builtin_amdgcn_mfma_f32_16x16x32_bf16(
                        af[mi], bq[kk][ni], acc[mi][ni], 0, 0, 0);
        }
        __syncthreads();                      // As reads done before next overwrite
#pragma unroll
        for (int i = 0; i < 8; ++i) offA[i] = offN[i];
    }

    // Epilogue: pre = acc + logc[n]*W1[last,h] + b1[h]; gelu(exact); dot W2; atomic out.
    // C/D layout (verified m89/m91): col = lane&15 (h), row = quad*4 + reg (n).
    const float* w1last = W1 + (size_t)KTOT * HID;
    float w1l[4], b1v[4], w2v[4];
#pragma unroll
    for (int ni = 0; ni < 4; ++ni) {
        int h = blkH * 128 + wh * 64 + ni * 16 + ln;
        w1l[ni] = w1last[h];
        b1v[ni] = b1[h];
        w2v[ni] = W2[h];
    }
    const int nbase = blkM * 128 + wm * 64 + quad * 4;
#pragma unroll
    for (int mi = 0; mi < 4; ++mi) {
#pragma unroll
        for (int rg = 0; rg < 4; ++rg) {
            const int n = nbase + mi * 16 + rg;
            const float lc = logc[n];
            float s = 0.0f;
#pragma unroll
            for (int ni = 0; ni < 4; ++ni) {
                float pre = acc[mi][ni][rg] + lc * w1l[ni] + b1v[ni];
                float hv = 0.5f * pre * (1.0f + erff(pre * 0.70710678118654752f));
                s += hv * w2v[ni];
            }
            s += __shfl_xor(s, 1);
            s += __shfl_xor(s, 2);
            s += __shfl_xor(s, 4);
            s += __shfl_xor(s, 8);
            if (ln == 0) atomicAdd(out + n, s);
        }
    }
}

// ---- launch --------------------------------------------------------------
extern "C" void kernel_launch(void* const* d_in, const int* in_sizes, int n_in,
                              void* d_out, int out_size, void* d_ws, size_t ws_size,
                              hipStream_t stream) {
    const float* q     = (const float*)d_in[0];
    const float* k     = (const float*)d_in[1];
    const int*   bidx  = (const int*)d_in[2];
    const int*   mask  = (const int*)d_in[3];
    const int*   count = (const int*)d_in[4];
    const float* W1    = (const float*)d_in[5];
    const float* b1    = (const float*)d_in[6];
    const float* W2    = (const float*)d_in[7];
    const float* b2    = (const float*)d_in[8];
    float* out = (float*)d_out;

    // workspace layout (bytes): buf 6,291,712 | w1f 17,039,360 | srcLUT 2,129,920 | logc 32,768
    char* ws = (char*)d_ws;
    ushort_t* buf    = (ushort_t*)(ws);
    ushort_t* w1f    = (ushort_t*)(ws + 6291712);
    int*      srcLUT = (int*)(ws + 6291712 + 17039360);
    float*    logc   = (float*)(ws + 6291712 + 17039360 + 2129920);

    prep_pack<<<PACK_BLOCKS, 256, 0, stream>>>(mask, bidx, count, b2, srcLUT, logc, out);
    prep_qk<<<QK_BLOCKS, 256, 0, stream>>>(q, k, buf);
    prep_w1<<<W1T_BLOCKS, 256, 0, stream>>>(W1, w1f);
    gemm_mlp<<<dim3(HID / 128, N_ROWS / 128), 256, 0, stream>>>(
        buf, w1f, srcLUT, logc, W1, b1, W2, out);
}